// Round 5
// baseline (322.556 us; speedup 1.0000x reference)
//
#include <hip/hip_runtime.h>

// Submanifold sparse conv 3x3x3, G=128, Cin=Cout=32.
// R5: M=64 implicit GEMM. One wave per 64-point tile: lane p owns point
// base+p -> 1 table lookup instr per offset k; idx shuffled to 4 A-frag
// gathers; B-frags (global, L2-hot) reused by 4 MFMAs each. Prep work
// (scatter + feats->bf16 + wt transpose->bf16) fused into one kernel.

#define GRID 128
#define CIN 32
#define COUT 32
#define NOFF 27
#define MT 64                  // points per wave

typedef __attribute__((ext_vector_type(8))) short bf16x8;
typedef __attribute__((ext_vector_type(4))) float f32x4;

__device__ inline unsigned short f2bf(float x) {
    union { float f; unsigned u; } v; v.f = x;
    unsigned r = v.u + 0x7fff + ((v.u >> 16) & 1);   // RTNE
    return (unsigned short)(r >> 16);
}

// Fused prep: feats fp32->bf16 (thread i: 4 elems), pos scatter (i<N),
// wt [27][ci][co] -> wtT [27][co][ci] bf16 (i<27648). All independent.
__global__ void prep_kernel(const float* __restrict__ feats,
                            const int* __restrict__ pos,
                            const float* __restrict__ wt,
                            int* __restrict__ table,
                            unsigned* __restrict__ featsB,
                            unsigned short* __restrict__ wtT,
                            int N, int elems4) {
    int i = blockIdx.x * 256 + threadIdx.x;
    if (i < elems4) {
        float4 v = *(const float4*)(feats + 4 * (size_t)i);
        unsigned lo = (unsigned)f2bf(v.x) | ((unsigned)f2bf(v.y) << 16);
        unsigned hi = (unsigned)f2bf(v.z) | ((unsigned)f2bf(v.w) << 16);
        uint2 o; o.x = lo; o.y = hi;
        *(uint2*)(featsB + 2 * (size_t)i) = o;
    }
    if (i < N) {
        int x = pos[3 * i], y = pos[3 * i + 1], z = pos[3 * i + 2];
        // numpy duplicate semantics: last write (max index) wins
        atomicMax(&table[(x * GRID + y) * GRID + z], i);
    }
    if (i < NOFF * CIN * COUT) {
        int k = i >> 10, r = i & 1023, ci = r >> 5, co = r & 31;
        wtT[k * 1024 + co * 32 + ci] = f2bf(wt[i]);
    }
}

__global__ __launch_bounds__(256, 4)
void conv_kernel(const unsigned short* __restrict__ featsB,
                 const int* __restrict__ pos,
                 const unsigned short* __restrict__ wtT,
                 const int* __restrict__ table,
                 float* __restrict__ out, int N, int numTiles) {
    int gtid = blockIdx.x * 256 + threadIdx.x;
    int tile = gtid >> 6;               // one wave per 64-point tile
    if (tile >= numTiles) return;
    int lane = threadIdx.x & 63;
    int m = lane & 15, quad = lane >> 4;
    int base = tile * MT;
    int g = base + lane;                // this lane's owned point
    bool gv = g < N;

    int x = 0, y = 0, z = 0;
    if (gv) { x = pos[3 * g]; y = pos[3 * g + 1]; z = pos[3 * g + 2]; }

    f32x4 acc[4][2];
#pragma unroll
    for (int f = 0; f < 4; ++f)
#pragma unroll
        for (int h = 0; h < 2; ++h)
            acc[f][h] = (f32x4){0.f, 0.f, 0.f, 0.f};

    const unsigned short* wb = wtT + quad * 8;   // + k*1024 + co*32

#pragma unroll
    for (int k = 0; k < NOFF; ++k) {
        const int dx = k / 9 - 1, dy = (k / 3) % 3 - 1, dz = k % 3 - 1;
        int nx = x + dx, ny = y + dy, nz = z + dz;
        int id = -1;
        if (gv && (unsigned)nx < GRID && (unsigned)ny < GRID && (unsigned)nz < GRID)
            id = table[(nx * GRID + ny) * GRID + nz];

        bf16x8 b0 = *(const bf16x8*)(wb + k * 1024 + m * 32);
        bf16x8 b1 = *(const bf16x8*)(wb + k * 1024 + (m + 16) * 32);

#pragma unroll
        for (int f = 0; f < 4; ++f) {
            int idf = __shfl(id, f * 16 + m, 64);
            bf16x8 a = {0, 0, 0, 0, 0, 0, 0, 0};
            if (idf >= 0)
                a = *(const bf16x8*)(featsB + (size_t)idf * CIN + quad * 8);
            acc[f][0] = __builtin_amdgcn_mfma_f32_16x16x32_bf16(a, b0, acc[f][0], 0, 0, 0);
            acc[f][1] = __builtin_amdgcn_mfma_f32_16x16x32_bf16(a, b1, acc[f][1], 0, 0, 0);
        }
    }

    // D layout: col = lane&15 = co, row = quad*4 + i = point within 16-frag
#pragma unroll
    for (int f = 0; f < 4; ++f) {
#pragma unroll
        for (int i = 0; i < 4; ++i) {
            int p = base + f * 16 + quad * 4 + i;
            if (p < N) {
                out[(size_t)p * COUT + m]      = acc[f][0][i];
                out[(size_t)p * COUT + m + 16] = acc[f][1][i];
            }
        }
    }
}

extern "C" void kernel_launch(void* const* d_in, const int* in_sizes, int n_in,
                              void* d_out, int out_size, void* d_ws, size_t ws_size,
                              hipStream_t stream) {
    const float* feats = (const float*)d_in[0];   // [N, 32]
    const int*   pos   = (const int*)d_in[1];     // [N, 3]
    const float* wt    = (const float*)d_in[2];   // [27, 32, 32]
    float* out = (float*)d_out;                   // [N, 32]
    int N = in_sizes[0] / CIN;

    char* ws = (char*)d_ws;
    int* table = (int*)ws;                                      // 8 MB
    size_t table_bytes = (size_t)GRID * GRID * GRID * sizeof(int);
    unsigned short* wtT = (unsigned short*)(ws + table_bytes);            // 55296 B
    unsigned short* featsB = (unsigned short*)(ws + table_bytes + 65536); // 32 MB

    hipMemsetAsync(table, 0xFF, table_bytes, stream);

    int elems4 = N * CIN / 4;      // 4M threads covers feats; N and wt smaller
    prep_kernel<<<(elems4 + 255) / 256, 256, 0, stream>>>(
        feats, pos, wt, table, (unsigned*)featsB, wtT, N, elems4);

    int numTiles = (N + MT - 1) / MT;
    int blocks = (numTiles + 3) / 4;   // 4 waves per block
    conv_kernel<<<blocks, 256, 0, stream>>>(featsB, pos, wtT, table, out, N, numTiles);
}

// Round 6
// 255.997 us; speedup vs baseline: 1.2600x; 1.2600x over previous
//
#include <hip/hip_runtime.h>

// Submanifold sparse conv 3x3x3, G=128, Cin=Cout=32.
// R6: M=16/wave implicit GEMM with forced MLP: all 27 table lookups
// precomputed into registers (clamped always-load, branch-free), W^T bf16
// staged in LDS (55.3KB, [k][co][ci]), 1024-thr blocks -> 2 blocks/CU.
// Per k: 1 bf16 row gather + 2 ds_read_b128 + 2 mfma_f32_16x16x32_bf16.

#define GRID 128
#define CIN 32
#define COUT 32
#define NOFF 27

typedef __attribute__((ext_vector_type(8))) short bf16x8;
typedef __attribute__((ext_vector_type(4))) float f32x4;

__device__ inline unsigned short f2bf(float x) {
    union { float f; unsigned u; } v; v.f = x;
    unsigned r = v.u + 0x7fff + ((v.u >> 16) & 1);   // RTNE
    return (unsigned short)(r >> 16);
}

// Fused prep: feats fp32->bf16 (thread i: 4 elems), pos scatter (i<N),
// wt [27][ci][co] -> wtT [27][co][ci] bf16 (i<27648). All independent.
__global__ void prep_kernel(const float* __restrict__ feats,
                            const int* __restrict__ pos,
                            const float* __restrict__ wt,
                            int* __restrict__ table,
                            unsigned* __restrict__ featsB,
                            unsigned short* __restrict__ wtT,
                            int N, int elems4) {
    int i = blockIdx.x * 256 + threadIdx.x;
    if (i < elems4) {
        float4 v = *(const float4*)(feats + 4 * (size_t)i);
        unsigned lo = (unsigned)f2bf(v.x) | ((unsigned)f2bf(v.y) << 16);
        unsigned hi = (unsigned)f2bf(v.z) | ((unsigned)f2bf(v.w) << 16);
        uint2 o; o.x = lo; o.y = hi;
        *(uint2*)(featsB + 2 * (size_t)i) = o;
    }
    if (i < N) {
        int x = pos[3 * i], y = pos[3 * i + 1], z = pos[3 * i + 2];
        // numpy duplicate semantics: last write (max index) wins
        atomicMax(&table[(x * GRID + y) * GRID + z], i);
    }
    if (i < NOFF * CIN * COUT) {
        int k = i >> 10, r = i & 1023, ci = r >> 5, co = r & 31;
        wtT[k * 1024 + co * 32 + ci] = f2bf(wt[i]);
    }
}

__global__ __launch_bounds__(1024, 8)
void conv_kernel(const unsigned short* __restrict__ featsB,
                 const int* __restrict__ pos,
                 const unsigned short* __restrict__ wtT,
                 const int* __restrict__ table,
                 float* __restrict__ out, int N) {
    __shared__ __align__(16) unsigned short ldsw[NOFF * 1024]; // 55296 B

    int tid = threadIdx.x;
    int wave = tid >> 6, lane = tid & 63;
    int m = lane & 15, quad = lane >> 4;
    int tile = blockIdx.x * 16 + wave;
    int base = tile * 16;
    int g = base + m;
    bool gv = g < N;                 // also false for tiles past the end

    int x = 0, y = 0, z = 0;
    if (gv) { x = pos[3 * g]; y = pos[3 * g + 1]; z = pos[3 * g + 2]; }
    int h = (x * GRID + y) * GRID + z;
    // per-axis validity, hoisted out of the k loop
    bool v0[3] = {gv && x > 0, gv, gv && x < GRID - 1};
    bool v1[3] = {gv && y > 0, gv, gv && y < GRID - 1};
    bool v2[3] = {gv && z > 0, gv, gv && z < GRID - 1};

    // Phase A: all 27 table lookups issued as independent loads (MLP).
    // Clamped always-load keeps the stream branch-free (table[0] is valid).
    int ids[NOFF];
#pragma unroll
    for (int k = 0; k < NOFF; ++k) {
        const int dx = k / 9, dy = (k / 3) % 3, dz = k % 3;   // 0..2
        bool ok = v0[dx] && v1[dy] && v2[dz];
        int hk = h + (dx - 1) * GRID * GRID + (dy - 1) * GRID + (dz - 1);
        hk = ok ? hk : 0;
        int id = table[hk];
        ids[k] = ok ? id : -1;
    }

    // Stage W^T into LDS while the table loads are in flight.
    {
        const uint4* src = (const uint4*)wtT;    // 3456 x 16B
        uint4* dst = (uint4*)ldsw;
        for (int e = tid; e < NOFF * 1024 * 2 / 16; e += 1024)
            dst[e] = src[e];
    }
    __syncthreads();

    f32x4 acc0 = {0.f, 0.f, 0.f, 0.f};
    f32x4 acc1 = {0.f, 0.f, 0.f, 0.f};
    const unsigned short* wb = ldsw + m * 32 + quad * 8;

    // Phase B: gathers all independent (addresses ready) -> pipelinable.
#pragma unroll
    for (int k = 0; k < NOFF; ++k) {
        int id = ids[k];
        int row = (id >= 0 ? id : 0) * CIN;
        bf16x8 a = *(const bf16x8*)(featsB + row + quad * 8);
        if (id < 0) a = (bf16x8){0, 0, 0, 0, 0, 0, 0, 0};

        bf16x8 b0 = *(const bf16x8*)(wb + k * 1024);        // co = m
        bf16x8 b1 = *(const bf16x8*)(wb + k * 1024 + 512);  // co = m+16

        acc0 = __builtin_amdgcn_mfma_f32_16x16x32_bf16(a, b0, acc0, 0, 0, 0);
        acc1 = __builtin_amdgcn_mfma_f32_16x16x32_bf16(a, b1, acc1, 0, 0, 0);
    }

    // D layout: col = lane&15 = co, row = quad*4 + i = point within tile
#pragma unroll
    for (int i = 0; i < 4; ++i) {
        int p = base + quad * 4 + i;
        if (p < N) {
            out[(size_t)p * COUT + m]      = acc0[i];
            out[(size_t)p * COUT + m + 16] = acc1[i];
        }
    }
}

extern "C" void kernel_launch(void* const* d_in, const int* in_sizes, int n_in,
                              void* d_out, int out_size, void* d_ws, size_t ws_size,
                              hipStream_t stream) {
    const float* feats = (const float*)d_in[0];   // [N, 32]
    const int*   pos   = (const int*)d_in[1];     // [N, 3]
    const float* wt    = (const float*)d_in[2];   // [27, 32, 32]
    float* out = (float*)d_out;                   // [N, 32]
    int N = in_sizes[0] / CIN;

    char* ws = (char*)d_ws;
    int* table = (int*)ws;                                      // 8 MB
    size_t table_bytes = (size_t)GRID * GRID * GRID * sizeof(int);
    unsigned short* wtT = (unsigned short*)(ws + table_bytes);            // 55296 B
    unsigned short* featsB = (unsigned short*)(ws + table_bytes + 65536); // 32 MB

    hipMemsetAsync(table, 0xFF, table_bytes, stream);

    int elems4 = N * CIN / 4;      // 4M threads covers feats; N and wt smaller
    prep_kernel<<<(elems4 + 255) / 256, 256, 0, stream>>>(
        feats, pos, wt, table, (unsigned*)featsB, wtT, N, elems4);

    int numTiles = (N + 15) / 16;
    int blocks = (numTiles + 15) / 16;   // 16 waves (1024 threads) per block
    conv_kernel<<<blocks, 1024, 0, stream>>>(featsB, pos, wtT, table, out, N);
}